// Round 22
// baseline (40.446 us; speedup 1.0000x reference)
//
#include <hip/hip_runtime.h>

typedef _Float16 f16x2 __attribute__((ext_vector_type(2)));

#define NPTS   385
#define GLMIN  (-6.0f)
#define INVH   32.0f

// Static device globals: allocated at module load (no hipMalloc in
// kernel_launch -> graph-capture safe). Rebuilt deterministically every call.
__device__ float    g_pre[2 * 170 * 52];          // fp32 pre-table
__device__ float    g_w1g[2 * 52];                // fp32 glicko column
__device__ unsigned g_tab[2 * 170 * 5 * NPTS];    // f16x2 (out0,out1) curves, 2.62 MB

// Stage 1: fp32 pre-table (W1[:, :50] @ emb + b1) and glicko column.
__global__ void pre_f32(const float* __restrict__ emb,
                        const float* __restrict__ W1a, const float* __restrict__ b1a,
                        const float* __restrict__ W1b, const float* __restrict__ b1b)
{
    const int team = blockIdx.y;
    const float* __restrict__ W1 = team ? W1b : W1a;
    const float* __restrict__ B1 = team ? b1b : b1a;
    const int k = threadIdx.x;
    if (blockIdx.x < 170) {
        const int cc = blockIdx.x;
        if (k < 52) {
            float v = 0.0f;
            if (k < 50) {
                v = B1[k];
                for (int d = 0; d < 50; ++d)
                    v = fmaf(W1[k * 51 + d], emb[cc * 50 + d], v);
            }
            g_pre[(team * 170 + cc) * 52 + k] = v;
        }
    } else if (k < 52) {
        g_w1g[team * 52 + k] = (k < 50) ? W1[k * 51 + 50] : 0.0f;
    }
}

// Stage 2: per (team, champ, gl-point) evaluate the team MLP exactly in fp32
// and project through each slot's Wf rows. out(gl) is piecewise-LINEAR in gl
// (ReLU net, input affine in gl), so stage-3's lerp is exact except in cells
// containing a knee (err <= dSlope*h/4 ~ 4e-4 at h = 1/32).
__global__ __launch_bounds__(256)
void build_table(const float* __restrict__ W2a, const float* __restrict__ b2a,
                 const float* __restrict__ W3a, const float* __restrict__ b3a,
                 const float* __restrict__ W2b, const float* __restrict__ b2b,
                 const float* __restrict__ W3b, const float* __restrict__ b3b,
                 const float* __restrict__ Wf)
{
    const int team = blockIdx.y;
    const int t = blockIdx.x * 256 + threadIdx.x;
    if (t >= 170 * NPTS) return;
    const int champ = t / NPTS, ip = t - champ * NPTS;
    const float gl = GLMIN + (float)ip * (1.0f / INVH);

    const float* __restrict__ W2 = team ? W2b : W2a;
    const float* __restrict__ B2 = team ? b2b : b2a;
    const float* __restrict__ W3 = team ? W3b : W3a;
    const float* __restrict__ B3 = team ? b3b : b3a;
    const float* __restrict__ pre = g_pre + (team * 170 + champ) * 52;
    const float* __restrict__ w1g = g_w1g + team * 52;

    float h2[25];
    #pragma unroll
    for (int m = 0; m < 25; ++m) h2[m] = B2[m];
    for (int k = 0; k < 50; ++k) {
        const float h1k = fmaxf(fmaf(gl, w1g[k], pre[k]), 0.0f);
        #pragma unroll
        for (int m = 0; m < 25; ++m)
            h2[m] = fmaf(W2[m * 50 + k], h1k, h2[m]);
    }
    float h2r[25];
    #pragma unroll
    for (int m = 0; m < 25; ++m) h2r[m] = fmaxf(h2[m], 0.0f);

    float h3[10];
    #pragma unroll
    for (int tt = 0; tt < 10; ++tt) {
        float a = B3[tt];
        #pragma unroll
        for (int m = 0; m < 25; ++m)
            a = fmaf(W3[tt * 25 + m], h2r[m], a);
        h3[tt] = fmaxf(a, 0.0f);
    }

    #pragma unroll
    for (int s = 0; s < 5; ++s) {
        float o0 = 0.0f, o1 = 0.0f;
        #pragma unroll
        for (int tt = 0; tt < 10; ++tt) {
            o0 = fmaf(Wf[team * 50 + s * 10 + tt],       h3[tt], o0);
            o1 = fmaf(Wf[100 + team * 50 + s * 10 + tt], h3[tt], o1);
        }
        f16x2 p;
        p.x = (_Float16)o0;
        p.y = (_Float16)o1;
        g_tab[((team * 170 + champ) * 5 + s) * NPTS + ip] =
            __builtin_bit_cast(unsigned, p);
    }
}

// Stage 3: 1 thread = 1 sample. 10 independent 8B gathers (L2-resident
// 2.6 MB table) + f32 lerp. ~80 VALU/sample; feat/out fully coalesced.
__global__ __launch_bounds__(256)
void table_main(const float* __restrict__ feat, const float* __restrict__ bf,
                float2* __restrict__ out, int nB)
{
    const int s = blockIdx.x * 256 + threadIdx.x;
    if (s >= nB) return;
    const float4* f4 = reinterpret_cast<const float4*>(feat + (size_t)s * 12);
    const float4 v0 = f4[0], v1 = f4[1], v2 = f4[2];
    const float fr_[12] = {v0.x, v0.y, v0.z, v0.w, v1.x, v1.y, v1.z, v1.w,
                           v2.x, v2.y, v2.z, v2.w};

    int   iT[2];
    float fT[2];
    #pragma unroll
    for (int team = 0; team < 2; ++team) {
        const float u = (fr_[team] - GLMIN) * INVH;
        int i = (int)u;
        i = (i < 0) ? 0 : ((i > NPTS - 2) ? NPTS - 2 : i);
        float f = u - (float)i;
        f = fminf(fmaxf(f, 0.0f), 1.0f);
        iT[team] = i;
        fT[team] = f;
    }

    float o0 = bf[0], o1 = bf[1];
    #pragma unroll
    for (int sl = 0; sl < 10; ++sl) {
        const int team = sl / 5;                  // compile-time after unroll
        const int ci = (int)fr_[2 + sl];
        const unsigned* __restrict__ p =
            g_tab + ((team * 170 + ci) * 5 + (sl - team * 5)) * NPTS + iT[team];
        const f16x2 ha = __builtin_bit_cast(f16x2, p[0]);
        const f16x2 hb = __builtin_bit_cast(f16x2, p[1]);
        const float a0 = (float)ha.x, a1 = (float)ha.y;
        const float b0 = (float)hb.x, b1 = (float)hb.y;
        o0 += fmaf(fT[team], b0 - a0, a0);
        o1 += fmaf(fT[team], b1 - a1, a1);
    }
    out[s] = make_float2(o0, o1);
}

extern "C" void kernel_launch(void* const* d_in, const int* in_sizes, int n_in,
                              void* d_out, int out_size, void* d_ws, size_t ws_size,
                              hipStream_t stream) {
    const float* feat = (const float*)d_in[0];
    const float* emb  = (const float*)d_in[1];
    const float* W1a  = (const float*)d_in[2];
    const float* b1a  = (const float*)d_in[3];
    const float* W2a  = (const float*)d_in[4];
    const float* b2a  = (const float*)d_in[5];
    const float* W3a  = (const float*)d_in[6];
    const float* b3a  = (const float*)d_in[7];
    const float* W1b  = (const float*)d_in[8];
    const float* b1b  = (const float*)d_in[9];
    const float* W2b  = (const float*)d_in[10];
    const float* b2b  = (const float*)d_in[11];
    const float* W3b  = (const float*)d_in[12];
    const float* b3b  = (const float*)d_in[13];
    const float* Wf   = (const float*)d_in[14];
    const float* bf   = (const float*)d_in[15];
    const int nB = in_sizes[0] / 12;

    pre_f32<<<dim3(171, 2), 64, 0, stream>>>(emb, W1a, b1a, W1b, b1b);
    build_table<<<dim3((170 * NPTS + 255) / 256, 2), 256, 0, stream>>>(
        W2a, b2a, W3a, b3a, W2b, b2b, W3b, b3b, Wf);
    table_main<<<(nB + 255) / 256, 256, 0, stream>>>(
        feat, bf, (float2*)d_out, nB);
}